// Round 1
// baseline (19.959 us; speedup 1.0000x reference)
//
#include <hip/hip_runtime.h>

#define KAPPA 0.276f
#define NMAT 128
#define NTRI 8256        // 128*129/2
#define NTRI4 2064       // NTRI/4
#define BATCH 1024

__global__ __launch_bounds__(256) void trace_kernel(const float* __restrict__ net_out,
                                                    const float* __restrict__ U1,
                                                    float* __restrict__ ws) {
    const int b = blockIdx.x;
    const int tid = threadIdx.x;

    __shared__ __align__(16) float lds[NTRI];
    __shared__ float red[4];

    // ---- stage triangle into LDS, accumulate sum of squares on the fly ----
    const float4* __restrict__ src = (const float4*)(net_out + (size_t)b * NTRI);
    float4* dst4 = (float4*)lds;
    float sq = 0.f;
    for (int idx = tid; idx < NTRI4; idx += 256) {
        float4 v = src[idx];
        dst4[idx] = v;
        sq += v.x * v.x + v.y * v.y + v.z * v.z + v.w * v.w;
    }
    __syncthreads();

    // ---- each thread: one (column, direction) neighbor dot product ----
    const int dir = tid >> 7;        // 0 -> +a neighbor, 1 -> +b neighbor
    const int k   = tid & 127;
    const int a   = k >> 4;
    const int bb  = (k >> 1) & 7;
    const int k2  = dir ? ((k & 0x70) | ((k + 2) & 0xF)) : ((k + 16) & 127);

    const float theta = U1[(size_t)b * 128 + dir * 64 + a * 8 + bb];
    const float coeff = cosf(theta);

    const int kmax = (k > k2) ? k : k2;
    float acc = 0.f;
    int tri = kmax * (kmax + 1) / 2;   // row offset of row kmax in triangle
    for (int i = kmax; i < NMAT; ++i) {
        acc += lds[tri + k] * lds[tri + k2];
        tri += i + 1;
    }

    // per-thread contribution: partial sum-of-squares + hop term
    float val = sq - 2.0f * KAPPA * coeff * acc;

    // ---- block reduction (4 waves of 64) ----
    #pragma unroll
    for (int off = 32; off > 0; off >>= 1)
        val += __shfl_down(val, off, 64);
    if ((tid & 63) == 0) red[tid >> 6] = val;
    __syncthreads();
    if (tid == 0)
        ws[b] = red[0] + red[1] + red[2] + red[3];
}

__global__ __launch_bounds__(256) void reduce_kernel(const float* __restrict__ ws,
                                                     float* __restrict__ out) {
    const int tid = threadIdx.x;
    float v = 0.f;
    for (int i = tid; i < BATCH; i += 256) v += ws[i];
    #pragma unroll
    for (int off = 32; off > 0; off >>= 1)
        v += __shfl_down(v, off, 64);
    __shared__ float red[4];
    if ((tid & 63) == 0) red[tid >> 6] = v;
    __syncthreads();
    if (tid == 0)
        out[0] = (red[0] + red[1] + red[2] + red[3]) * (1.0f / (128.0f * (float)BATCH));
}

extern "C" void kernel_launch(void* const* d_in, const int* in_sizes, int n_in,
                              void* d_out, int out_size, void* d_ws, size_t ws_size,
                              hipStream_t stream) {
    const float* net_out = (const float*)d_in[0];  // (1024, 8256) fp32
    const float* U1      = (const float*)d_in[1];  // (1024, 2, 8, 8) fp32
    float* out = (float*)d_out;                    // scalar fp32
    float* ws  = (float*)d_ws;                     // >= 1024 floats

    trace_kernel<<<BATCH, 256, 0, stream>>>(net_out, U1, ws);
    reduce_kernel<<<1, 256, 0, stream>>>(ws, out);
}